// Round 3
// baseline (12157.218 us; speedup 1.0000x reference)
//
#include <hip/hip_runtime.h>
#include <stdint.h>

#define DI __device__ __forceinline__

typedef short s16x8 __attribute__((ext_vector_type(8)));
typedef float f32x4 __attribute__((ext_vector_type(4)));

// ---- constants ----
#define NG   2048
#define NP   512
#define TT   100
#define BB   256
#define N4   8192   // 4*NG
#define MR   25600  // B*T
#define NBLK 256    // persistent grid size

DI unsigned short f32_to_bf16(float f) {
  union { float f; uint32_t u; } x; x.f = f;
  uint32_t r = x.u + 0x7fffu + ((x.u >> 16) & 1u);
  return (unsigned short)(r >> 16);
}

DI void async16(const void* g, void* l) {
  __builtin_amdgcn_global_load_lds((const __attribute__((address_space(1))) void*)g,
                                   (__attribute__((address_space(3))) void*)l,
                                   16, 0, 0);
}

DI f32x4 mfma16(s16x8 a, s16x8 b, f32x4 c) {
  return __builtin_amdgcn_mfma_f32_16x16x32_bf16(a, b, c, 0, 0, 0);
}

// ---- software grid barrier (generation-based, agent scope) ----
// Safe: grid=256 blocks, 8 waves + 48KB LDS each -> >=3 blocks/CU capacity,
// stream is empty at launch -> all blocks co-resident, spin cannot starve.
DI void grid_barrier(unsigned* cnt, unsigned* gen) {
  __threadfence();                     // release: publish this thread's stores
  __syncthreads();                     // whole block arrived
  if (threadIdx.x == 0) {
    unsigned g = __hip_atomic_load(gen, __ATOMIC_RELAXED, __HIP_MEMORY_SCOPE_AGENT);
    unsigned a = __hip_atomic_fetch_add(cnt, 1u, __ATOMIC_ACQ_REL, __HIP_MEMORY_SCOPE_AGENT);
    if (a + 1u == (unsigned)NBLK) {
      __hip_atomic_store(cnt, 0u, __ATOMIC_RELAXED, __HIP_MEMORY_SCOPE_AGENT);
      __hip_atomic_fetch_add(gen, 1u, __ATOMIC_RELEASE, __HIP_MEMORY_SCOPE_AGENT);
    } else {
      while (__hip_atomic_load(gen, __ATOMIC_ACQUIRE, __HIP_MEMORY_SCOPE_AGENT) == g)
        __builtin_amdgcn_s_sleep(2);
    }
  }
  __syncthreads();
  __threadfence();                     // acquire: discard stale cached lines
}

__global__ __launch_bounds__(64) void k_zero2(unsigned* p) {
  if (threadIdx.x < 2) p[threadIdx.x] = 0u;
}

// =====================================================================
// Pipelined bf16 MFMA core: BM x 128 tile, BK=64, 512 threads (8 waves
// as 2x4), double-buffered LDS, prefetch-next-before-compute, XOR-swizzled
// LDS (linear global_load_lds dest + inverse-swizzled global source col +
// swizzled ds_read).  A row-major [M][K] bf16, Bt n-major [N][K] bf16.
// acc layout: acc[fm*2+fn], FM = BM/32, FN = 2.
// sA: 2*BM*64 shorts. sB: 2*128*64 shorts.
// =====================================================================
template <int BM>
DI void gemm_core_p(const unsigned short* __restrict__ A, int lda, int m0,
                    const unsigned short* __restrict__ Bt, int ldb, int n0, int K,
                    unsigned short* sA, unsigned short* sB, f32x4* acc) {
  constexpr int FM = BM / 32;
  const int tid  = threadIdx.x;
  const int wave = tid >> 6;
  const int lane = tid & 63;
  const int quad = lane >> 4;
  const int lr   = lane & 15;
  const int wm   = wave >> 2;
  const int wn   = wave & 3;
  const int lr8  = lane >> 3;              // row within 8-row chunk
  const int lc8  = lane & 7;               // 16B column chunk
  const int scol = (lc8 ^ lr8) << 3;       // inverse-swizzled source col (shorts)

  const int nkt = K >> 6;
  int buf = 0;

  auto stage = [&](int bsel, int k0) {
    unsigned short* dA = sA + bsel * (BM * 64);
    unsigned short* dB = sB + bsel * (128 * 64);
#pragma unroll
    for (int c = 0; c < BM / 64; ++c) {
      int rbase = wave * (BM / 8) + c * 8;
      const unsigned short* g = A + (size_t)(m0 + rbase + lr8) * lda + (k0 + scol);
      async16(g, dA + rbase * 64);         // wave-uniform LDS base; HW adds lane*16
    }
#pragma unroll
    for (int c = 0; c < 2; ++c) {
      int rbase = wave * 16 + c * 8;
      const unsigned short* g = Bt + (size_t)(n0 + rbase + lr8) * ldb + (k0 + scol);
      async16(g, dB + rbase * 64);
    }
  };

  stage(0, 0);
  __syncthreads();                          // drains vmcnt -> buf0 ready
  for (int kt = 0; kt < nkt; ++kt) {
    if (kt + 1 < nkt) stage(buf ^ 1, (kt + 1) << 6);   // prefetch next tile
    const char* cA = (const char*)(sA + buf * (BM * 64));
    const char* cB = (const char*)(sB + buf * (128 * 64));
#pragma unroll
    for (int ks = 0; ks < 2; ++ks) {
      s16x8 af[FM], bfr[2];
#pragma unroll
      for (int fm = 0; fm < FM; ++fm) {
        int row = wm * (BM / 2) + fm * 16 + lr;
        int off = row * 128 + ((ks * 64 + quad * 16) ^ ((row & 7) << 4));
        af[fm] = *(const s16x8*)(cA + off);
      }
#pragma unroll
      for (int fn = 0; fn < 2; ++fn) {
        int col = wn * 32 + fn * 16 + lr;
        int off = col * 128 + ((ks * 64 + quad * 16) ^ ((col & 7) << 4));
        bfr[fn] = *(const s16x8*)(cB + off);
      }
#pragma unroll
      for (int fm = 0; fm < FM; ++fm)
#pragma unroll
        for (int fn = 0; fn < 2; ++fn)
          acc[fm * 2 + fn] = mfma16(af[fm], bfr[fn], acc[fm * 2 + fn]);
    }
    __syncthreads();   // one barrier/iter: drains this iter's prefetch too
    buf ^= 1;
  }
}

// =====================================================================
// Transpose + fp32->bf16 convert. src fp32 [R][C] row-major ->
// dst bf16 [n(C)][R] row-major. MODE 0: n = c + noff. MODE 1 (lstm_U gate
// interleave): n = (c & 2047)*4 + (c >> 11).
// =====================================================================
template <int MODE>
__global__ __launch_bounds__(256) void k_transpose_bf16(
    const float* __restrict__ src, unsigned short* __restrict__ dst,
    int R, int C, int noff) {
  __shared__ unsigned short tile[64][65];
  int tr0 = blockIdx.x * 64;
  int tc0 = blockIdx.y * 64;
  int tid = threadIdx.x;
#pragma unroll
  for (int i = 0; i < 16; ++i) {
    int idx = tid + i * 256;
    int r = idx >> 6, c = idx & 63;
    tile[r][c] = f32_to_bf16(src[(size_t)(tr0 + r) * C + (tc0 + c)]);
  }
  __syncthreads();
#pragma unroll
  for (int i = 0; i < 16; ++i) {
    int idx = tid + i * 256;
    int cc = idx >> 6, r = idx & 63;
    int c = tc0 + cc;
    int n = (MODE == 0) ? (c + noff) : (((c & 2047) << 2) | (c >> 11));
    dst[(size_t)n * R + (tr0 + r)] = tile[r][cc];
  }
}

__global__ __launch_bounds__(256) void k_cvt(const float* __restrict__ src,
                                             unsigned short* __restrict__ dst, int n) {
  int i = blockIdx.x * 256 + threadIdx.x;
  if (i < n) dst[i] = f32_to_bf16(src[i]);
}

// ---- W2 = M_W @ lstm_W, bias2 = M_b @ lstm_W + lstm_b (gate-reordered) ----
__global__ __launch_bounds__(256) void k_prep_xw_part(
    const float* __restrict__ lstm_W, const float* __restrict__ M_W,
    const float* __restrict__ M_b, float* __restrict__ part) {
  int c = blockIdx.x * 256 + threadIdx.x;   // 0..8191 original column
  int kc = blockIdx.y;
  int k0 = kc * 128;
  float a0 = 0.f, a1 = 0.f, ab = 0.f;
  for (int k = k0; k < k0 + 128; ++k) {
    float w = lstm_W[(size_t)k * N4 + c];
    a0 += M_W[k] * w;
    a1 += M_W[NG + k] * w;
    ab += M_b[k] * w;
  }
  float* p = part + (size_t)kc * 3 * N4;
  p[c] = a0; p[N4 + c] = a1; p[2 * N4 + c] = ab;
}

__global__ __launch_bounds__(256) void k_prep_xw_reduce(
    const float* __restrict__ part, const float* __restrict__ lstm_b,
    float* __restrict__ W2r, float* __restrict__ b2r) {
  int c = blockIdx.x * 256 + threadIdx.x;
  float a0 = 0.f, a1 = 0.f, ab = 0.f;
  for (int kc = 0; kc < 16; ++kc) {
    const float* p = part + (size_t)kc * 3 * N4;
    a0 += p[c]; a1 += p[N4 + c]; ab += p[2 * N4 + c];
  }
  int n = ((c & 2047) << 2) | (c >> 11);   // gate interleave
  W2r[n] = a0; W2r[N4 + n] = a1; b2r[n] = ab + lstm_b[c];
}

// ---- encoders: [h0 | c0] = p0 @ [enc1_W ; enc2_W] packed as N=4096 ----
__global__ __launch_bounds__(512) void k_enc(
    const unsigned short* __restrict__ p0b, const unsigned short* __restrict__ encWt,
    const float* __restrict__ enc1_b, const float* __restrict__ enc2_b,
    unsigned short* __restrict__ hbf, float* __restrict__ cfp) {
  __shared__ __align__(16) unsigned short sA[2 * 64 * 64];
  __shared__ __align__(16) unsigned short sB[2 * 128 * 64];
  int m0 = blockIdx.x * 64, n0 = blockIdx.y * 128;
  const f32x4 vzero = {0.f, 0.f, 0.f, 0.f};
  f32x4 acc[4];
#pragma unroll
  for (int i = 0; i < 4; ++i) acc[i] = vzero;
  gemm_core_p<64>(p0b, NP, m0, encWt, NP, n0, NP, sA, sB, acc);

  const int tid = threadIdx.x, wave = tid >> 6, lane = tid & 63;
  const int quad = lane >> 4, lr = lane & 15, wm = wave >> 2, wn = wave & 3;
#pragma unroll
  for (int fm = 0; fm < 2; ++fm)
#pragma unroll
    for (int fn = 0; fn < 2; ++fn)
#pragma unroll
      for (int reg = 0; reg < 4; ++reg) {
        int grow = m0 + wm * 32 + fm * 16 + quad * 4 + reg;
        int gcol = n0 + wn * 32 + fn * 16 + lr;
        float val = acc[fm * 2 + fn][reg];
        if (gcol < NG)
          hbf[(size_t)grow * NG + gcol] = f32_to_bf16(val + enc1_b[gcol]);
        else
          cfp[(size_t)grow * NG + (gcol - NG)] = val + enc2_b[gcol - NG];
      }
}

// ---- persistent recurrence: all 100 LSTM steps, software grid barrier ----
// 256 blocks (4 mt x 64 nt, XCD swizzle), 512 threads, tile 64x128.
__global__ __launch_bounds__(512) void k_steps(
    const unsigned short* __restrict__ Ut,
    const float* __restrict__ vv, const float* __restrict__ W2r,
    const float* __restrict__ b2r, float* __restrict__ cfp,
    unsigned short* __restrict__ hb0, unsigned short* __restrict__ hb1,
    unsigned short* __restrict__ hs, unsigned* __restrict__ bar) {
  // sA 2*64*64 shorts (16KB) + sB 2*128*64 shorts (32KB) = 48KB,
  // reused as z [64][132] f32 (33.8KB) in the epilogue.
  __shared__ __align__(16) char smem[49152];
  unsigned short* sA = (unsigned short*)smem;
  unsigned short* sB = (unsigned short*)(smem + 16384);

  int bid = blockIdx.x;                 // XCD-aware swizzle keeps Ut panel L2-resident
  int xcd = bid & 7, s = bid >> 3;
  int mt = s >> 3, nsub = s & 7;
  int nt = xcd * 8 + nsub;
  int m0 = mt * 64, n0 = nt * 128;
  int tid = threadIdx.x;
  const int wave = tid >> 6, lane = tid & 63;
  const int quad = lane >> 4, lr = lane & 15, wm = wave >> 2, wn = wave & 3;

  // gate-epilogue constants, invariant over t -> hoisted to registers
  const int j = tid & 31;
  const int gbase = n0 + 4 * j;
  const float4 w2a = *(const float4*)(W2r + gbase);
  const float4 w2b = *(const float4*)(W2r + N4 + gbase);
  const float4 bb  = *(const float4*)(b2r + gbase);
  const int cell = (n0 >> 2) + j;
  const int r0 = tid >> 5;

  for (int t = 0; t < TT; ++t) {
    const unsigned short* hin = (t & 1) ? hb1 : hb0;
    unsigned short* hout      = (t & 1) ? hb0 : hb1;

    const f32x4 vzero = {0.f, 0.f, 0.f, 0.f};
    f32x4 acc[4];
#pragma unroll
    for (int i = 0; i < 4; ++i) acc[i] = vzero;
    gemm_core_p<64>(hin, NG, m0, Ut, NG, n0, NG, sA, sB, acc);

    // phase 1: z -> LDS (reuse staging; safe after final in-loop barrier)
    float* zs = (float*)smem;
#pragma unroll
    for (int fm = 0; fm < 2; ++fm)
#pragma unroll
      for (int fn = 0; fn < 2; ++fn)
#pragma unroll
        for (int reg = 0; reg < 4; ++reg) {
          int r  = wm * 32 + fm * 16 + quad * 4 + reg;
          int cc = wn * 32 + fn * 16 + lr;
          zs[r * 132 + cc] = acc[fm * 2 + fn][reg];
        }
    __syncthreads();
    // phase 2: gate update, 64 rows x 32 cells
#pragma unroll
    for (int i = 0; i < 4; ++i) {
      int r = r0 + i * 16;
      int b = m0 + r;
      const float2 vb = *(const float2*)(vv + ((size_t)b * TT + t) * 2);
      float4 z4 = *(const float4*)(zs + r * 132 + 4 * j);
      float zi = z4.x + vb.x * w2a.x + vb.y * w2b.x + bb.x;
      float zf = z4.y + vb.x * w2a.y + vb.y * w2b.y + bb.y;
      float zg = z4.z + vb.x * w2a.z + vb.y * w2b.z + bb.z;
      float zo = z4.w + vb.x * w2a.w + vb.y * w2b.w + bb.w;
      float i_ = 1.f / (1.f + __expf(-zi));
      float f_ = 1.f / (1.f + __expf(-zf));
      float g_ = fmaxf(zg, 0.f);
      float o_ = 1.f / (1.f + __expf(-zo));
      size_t ci = (size_t)b * NG + cell;
      float cn = f_ * cfp[ci] + i_ * g_;
      cfp[ci] = cn;
      unsigned short hb = f32_to_bf16(o_ * fmaxf(cn, 0.f));
      hout[ci] = hb;
      hs[((size_t)t * BB + b) * NG + cell] = hb;
    }
    if (t + 1 < TT) grid_barrier(bar, bar + 1);  // publish hout, await all blocks
  }
}

// ---- g_cells = relu(hs @ dense_W + dense_b) -> bf16 ----
// 1D grid 3200: each XCD owns a fixed pair of n-tiles (B panel 1MB stays
// L2-resident); all XCDs sweep mt in lockstep (A fetched from HBM once,
// L3 serves the other XCDs).
__global__ __launch_bounds__(512) void k_dense(
    const unsigned short* __restrict__ hs, const unsigned short* __restrict__ dWt,
    const float* __restrict__ dense_b, unsigned short* __restrict__ gc) {
  __shared__ __align__(16) unsigned short sA[2 * 128 * 64];
  __shared__ __align__(16) unsigned short sB[2 * 128 * 64];
  int bid = blockIdx.x;
  int mt = bid >> 4;
  int r4 = bid & 15;
  int nt = ((r4 & 7) << 1) | (r4 >> 3);   // bid%8 -> fixed nt pair per XCD
  int m0 = mt * 128, n0 = nt * 128;
  const f32x4 vzero = {0.f, 0.f, 0.f, 0.f};
  f32x4 acc[8];
#pragma unroll
  for (int i = 0; i < 8; ++i) acc[i] = vzero;
  gemm_core_p<128>(hs, NG, m0, dWt, NG, n0, NG, sA, sB, acc);

  const int tid = threadIdx.x, wave = tid >> 6, lane = tid & 63;
  const int quad = lane >> 4, lr = lane & 15, wm = wave >> 2, wn = wave & 3;
#pragma unroll
  for (int fm = 0; fm < 4; ++fm)
#pragma unroll
    for (int fn = 0; fn < 2; ++fn)
#pragma unroll
      for (int reg = 0; reg < 4; ++reg) {
        int grow = m0 + wm * 64 + fm * 16 + quad * 4 + reg;
        int gcol = n0 + wn * 32 + fn * 16 + lr;
        float val = fmaxf(acc[fm * 2 + fn][reg] + dense_b[gcol], 0.f);
        gc[(size_t)grow * NG + gcol] = f32_to_bf16(val);
      }
}

// ---- place_preds = g_cells @ dec_W + dec_b (fp32 out, [B][T][Np]) ----
__global__ __launch_bounds__(512) void k_dec(
    const unsigned short* __restrict__ gc, const unsigned short* __restrict__ decWt,
    const float* __restrict__ dec_b, float* __restrict__ out) {
  __shared__ __align__(16) unsigned short sA[2 * 128 * 64];
  __shared__ __align__(16) unsigned short sB[2 * 128 * 64];
  int m0 = blockIdx.x * 128, n0 = blockIdx.y * 128;
  const f32x4 vzero = {0.f, 0.f, 0.f, 0.f};
  f32x4 acc[8];
#pragma unroll
  for (int i = 0; i < 8; ++i) acc[i] = vzero;
  gemm_core_p<128>(gc, NG, m0, decWt, NG, n0, NG, sA, sB, acc);

  const int tid = threadIdx.x, wave = tid >> 6, lane = tid & 63;
  const int quad = lane >> 4, lr = lane & 15, wm = wave >> 2, wn = wave & 3;
#pragma unroll
  for (int fm = 0; fm < 4; ++fm)
#pragma unroll
    for (int fn = 0; fn < 2; ++fn)
#pragma unroll
      for (int reg = 0; reg < 4; ++reg) {
        int grow = m0 + wm * 64 + fm * 16 + quad * 4 + reg;   // t*256+b
        int gcol = n0 + wn * 32 + fn * 16 + lr;               // 0..511
        int tt = grow >> 8, b = grow & 255;
        out[((size_t)b * TT + tt) * NP + gcol] = acc[fm * 2 + fn][reg] + dec_b[gcol];
      }
}

// =====================================================================
extern "C" void kernel_launch(void* const* d_in, const int* in_sizes, int n_in,
                              void* d_out, int out_size, void* d_ws, size_t ws_size,
                              hipStream_t stream) {
  (void)in_sizes; (void)n_in; (void)out_size; (void)ws_size;
  const float* v       = (const float*)d_in[0];
  const float* p0      = (const float*)d_in[1];
  const float* enc1_W  = (const float*)d_in[2];
  const float* enc1_b  = (const float*)d_in[3];
  const float* enc2_W  = (const float*)d_in[4];
  const float* enc2_b  = (const float*)d_in[5];
  const float* M_W     = (const float*)d_in[6];
  const float* M_b     = (const float*)d_in[7];
  const float* lstm_W  = (const float*)d_in[8];
  const float* lstm_U  = (const float*)d_in[9];
  const float* lstm_b  = (const float*)d_in[10];
  const float* dense_W = (const float*)d_in[11];
  const float* dense_b = (const float*)d_in[12];
  const float* dec_W   = (const float*)d_in[13];
  const float* dec_b   = (const float*)d_in[14];
  float* out = (float*)d_out;

  char* ws = (char*)d_ws;
  size_t off = 0;
  auto alloc = [&](size_t bytes) {
    char* p = ws + off;
    off += (bytes + 255) & ~(size_t)255;
    return p;
  };
  unsigned short* Ut    = (unsigned short*)alloc((size_t)N4 * NG * 2);   // 32 MB
  unsigned short* dWt   = (unsigned short*)alloc((size_t)NG * NG * 2);   // 8 MB
  unsigned short* decWt = (unsigned short*)alloc((size_t)NP * NG * 2);   // 2 MB
  unsigned short* encWt = (unsigned short*)alloc((size_t)2 * NG * NP * 2);
  unsigned short* p0b   = (unsigned short*)alloc((size_t)BB * NP * 2);
  float* W2r  = (float*)alloc((size_t)2 * N4 * 4);
  float* b2r  = (float*)alloc((size_t)N4 * 4);
  float* part = (float*)alloc((size_t)16 * 3 * N4 * 4);
  float* cfp  = (float*)alloc((size_t)BB * NG * 4);
  unsigned short* hb0 = (unsigned short*)alloc((size_t)BB * NG * 2);
  unsigned short* hb1 = (unsigned short*)alloc((size_t)BB * NG * 2);
  unsigned short* hs  = (unsigned short*)alloc((size_t)MR * NG * 2);     // 100 MB
  unsigned short* gc  = (unsigned short*)alloc((size_t)MR * NG * 2);     // 100 MB
  unsigned* bar = (unsigned*)alloc(256);                                 // barrier words

  dim3 blk(256), blk5(512);
  // barrier init (fresh every launch/replay)
  k_zero2<<<dim3(1), dim3(64), 0, stream>>>(bar);
  // weight conversion / transposes
  k_transpose_bf16<1><<<dim3(32, 128), blk, 0, stream>>>(lstm_U, Ut, NG, N4, 0);
  k_transpose_bf16<0><<<dim3(32, 32), blk, 0, stream>>>(dense_W, dWt, NG, NG, 0);
  k_transpose_bf16<0><<<dim3(32, 8), blk, 0, stream>>>(dec_W, decWt, NG, NP, 0);
  k_transpose_bf16<0><<<dim3(8, 32), blk, 0, stream>>>(enc1_W, encWt, NP, NG, 0);
  k_transpose_bf16<0><<<dim3(8, 32), blk, 0, stream>>>(enc2_W, encWt, NP, NG, NG);
  k_cvt<<<dim3(512), blk, 0, stream>>>(p0, p0b, BB * NP);
  // rank-2 collapse of input path
  k_prep_xw_part<<<dim3(32, 16), blk, 0, stream>>>(lstm_W, M_W, M_b, part);
  k_prep_xw_reduce<<<dim3(32), blk, 0, stream>>>(part, lstm_b, W2r, b2r);
  // initial state
  k_enc<<<dim3(4, 32), blk5, 0, stream>>>(p0b, encWt, enc1_b, enc2_b, hb0, cfp);
  // recurrence: one persistent kernel, 100 steps, software grid barrier
  k_steps<<<dim3(NBLK), blk5, 0, stream>>>(Ut, v, W2r, b2r, cfp, hb0, hb1, hs, bar);
  // readout
  k_dense<<<dim3(3200), blk5, 0, stream>>>(hs, dWt, dense_b, gc);
  k_dec<<<dim3(200, 4), blk5, 0, stream>>>(gc, decWt, dec_b, out);
}

// Round 4
// 2134.666 us; speedup vs baseline: 5.6951x; 5.6951x over previous
//
#include <hip/hip_runtime.h>
#include <stdint.h>

#define DI __device__ __forceinline__

typedef short s16x8 __attribute__((ext_vector_type(8)));
typedef float f32x4 __attribute__((ext_vector_type(4)));

// ---- constants ----
#define NG   2048
#define NP   512
#define TT   100
#define BB   256
#define N4   8192   // 4*NG
#define MR   25600  // B*T
#define NBLK 256    // persistent grid size

DI unsigned short f32_to_bf16(float f) {
  union { float f; uint32_t u; } x; x.f = f;
  uint32_t r = x.u + 0x7fffu + ((x.u >> 16) & 1u);
  return (unsigned short)(r >> 16);
}

DI void async16(const void* g, void* l) {
  __builtin_amdgcn_global_load_lds((const __attribute__((address_space(1))) void*)g,
                                   (__attribute__((address_space(3))) void*)l,
                                   16, 0, 0);
}

DI f32x4 mfma16(s16x8 a, s16x8 b, f32x4 c) {
  return __builtin_amdgcn_mfma_f32_16x16x32_bf16(a, b, c, 0, 0, 0);
}

__global__ __launch_bounds__(256) void k_zero(unsigned* p) {
  if (threadIdx.x < 160) p[threadIdx.x] = 0u;
}

// ---- software grid barrier: monotonic counters, RELAXED agent atomics ----
// No fences: all cross-XCD data (hs) moves via sc1 write-through stores
// (drained by vmcnt(0) before arrival) and first-touch cached reads.
// Layout: bar[xcd*16] per-XCD counters (64B apart), bar[128] global, bar[144] gen.
// Safe: 96KB LDS -> exactly 1 block/CU, grid=256=CU count, empty stream at
// launch -> all blocks co-resident, spin cannot starve.
DI void grid_barrier2(unsigned* bar, int xcd, int t) {
  asm volatile("s_waitcnt vmcnt(0)" ::: "memory");  // h-stores globally visible
  __syncthreads();
  if (threadIdx.x == 0) {
    unsigned a = __hip_atomic_fetch_add(bar + xcd * 16, 1u,
                                        __ATOMIC_RELAXED, __HIP_MEMORY_SCOPE_AGENT);
    if (a + 1u == 32u * (unsigned)(t + 1)) {        // last block of this XCD
      unsigned g2 = __hip_atomic_fetch_add(bar + 128, 1u,
                                           __ATOMIC_RELAXED, __HIP_MEMORY_SCOPE_AGENT);
      if (g2 + 1u == 8u * (unsigned)(t + 1))        // last XCD
        __hip_atomic_store(bar + 144, (unsigned)(t + 1),
                           __ATOMIC_RELAXED, __HIP_MEMORY_SCOPE_AGENT);
    }
    while (__hip_atomic_load(bar + 144, __ATOMIC_RELAXED,
                             __HIP_MEMORY_SCOPE_AGENT) < (unsigned)(t + 1))
      __builtin_amdgcn_s_sleep(8);
  }
  __syncthreads();
}

// =====================================================================
// Pipelined bf16 MFMA core (non-persistent kernels): BM x 128 tile, BK=64,
// 512 threads (8 waves as 2x4), double-buffered LDS, prefetch-1,
// XOR-swizzled LDS (linear global_load_lds dest + inverse-swizzled global
// source col + swizzled ds_read). A row-major [M][K] bf16, Bt n-major.
// =====================================================================
template <int BM>
DI void gemm_core_p(const unsigned short* __restrict__ A, int lda, int m0,
                    const unsigned short* __restrict__ Bt, int ldb, int n0, int K,
                    unsigned short* sA, unsigned short* sB, f32x4* acc) {
  constexpr int FM = BM / 32;
  const int tid  = threadIdx.x;
  const int wave = tid >> 6;
  const int lane = tid & 63;
  const int quad = lane >> 4;
  const int lr   = lane & 15;
  const int wm   = wave >> 2;
  const int wn   = wave & 3;
  const int lr8  = lane >> 3;
  const int lc8  = lane & 7;
  const int scol = (lc8 ^ lr8) << 3;

  const int nkt = K >> 6;
  int buf = 0;

  auto stage = [&](int bsel, int k0) {
    unsigned short* dA = sA + bsel * (BM * 64);
    unsigned short* dB = sB + bsel * (128 * 64);
#pragma unroll
    for (int c = 0; c < BM / 64; ++c) {
      int rbase = wave * (BM / 8) + c * 8;
      const unsigned short* g = A + (size_t)(m0 + rbase + lr8) * lda + (k0 + scol);
      async16(g, dA + rbase * 64);
    }
#pragma unroll
    for (int c = 0; c < 2; ++c) {
      int rbase = wave * 16 + c * 8;
      const unsigned short* g = Bt + (size_t)(n0 + rbase + lr8) * ldb + (k0 + scol);
      async16(g, dB + rbase * 64);
    }
  };

  stage(0, 0);
  __syncthreads();
  for (int kt = 0; kt < nkt; ++kt) {
    if (kt + 1 < nkt) stage(buf ^ 1, (kt + 1) << 6);
    const char* cA = (const char*)(sA + buf * (BM * 64));
    const char* cB = (const char*)(sB + buf * (128 * 64));
#pragma unroll
    for (int ks = 0; ks < 2; ++ks) {
      s16x8 af[FM], bfr[2];
#pragma unroll
      for (int fm = 0; fm < FM; ++fm) {
        int row = wm * (BM / 2) + fm * 16 + lr;
        int off = row * 128 + ((ks * 64 + quad * 16) ^ ((row & 7) << 4));
        af[fm] = *(const s16x8*)(cA + off);
      }
#pragma unroll
      for (int fn = 0; fn < 2; ++fn) {
        int col = wn * 32 + fn * 16 + lr;
        int off = col * 128 + ((ks * 64 + quad * 16) ^ ((col & 7) << 4));
        bfr[fn] = *(const s16x8*)(cB + off);
      }
#pragma unroll
      for (int fm = 0; fm < FM; ++fm)
#pragma unroll
        for (int fn = 0; fn < 2; ++fn)
          acc[fm * 2 + fn] = mfma16(af[fm], bfr[fn], acc[fm * 2 + fn]);
    }
    __syncthreads();
    buf ^= 1;
  }
}

// =====================================================================
// Transpose + fp32->bf16 convert.
// =====================================================================
template <int MODE>
__global__ __launch_bounds__(256) void k_transpose_bf16(
    const float* __restrict__ src, unsigned short* __restrict__ dst,
    int R, int C, int noff) {
  __shared__ unsigned short tile[64][65];
  int tr0 = blockIdx.x * 64;
  int tc0 = blockIdx.y * 64;
  int tid = threadIdx.x;
#pragma unroll
  for (int i = 0; i < 16; ++i) {
    int idx = tid + i * 256;
    int r = idx >> 6, c = idx & 63;
    tile[r][c] = f32_to_bf16(src[(size_t)(tr0 + r) * C + (tc0 + c)]);
  }
  __syncthreads();
#pragma unroll
  for (int i = 0; i < 16; ++i) {
    int idx = tid + i * 256;
    int cc = idx >> 6, r = idx & 63;
    int c = tc0 + cc;
    int n = (MODE == 0) ? (c + noff) : (((c & 2047) << 2) | (c >> 11));
    dst[(size_t)n * R + (tr0 + r)] = tile[r][cc];
  }
}

__global__ __launch_bounds__(256) void k_cvt(const float* __restrict__ src,
                                             unsigned short* __restrict__ dst, int n) {
  int i = blockIdx.x * 256 + threadIdx.x;
  if (i < n) dst[i] = f32_to_bf16(src[i]);
}

// ---- W2 = M_W @ lstm_W, bias2 = M_b @ lstm_W + lstm_b (gate-reordered) ----
__global__ __launch_bounds__(256) void k_prep_xw_part(
    const float* __restrict__ lstm_W, const float* __restrict__ M_W,
    const float* __restrict__ M_b, float* __restrict__ part) {
  int c = blockIdx.x * 256 + threadIdx.x;
  int kc = blockIdx.y;
  int k0 = kc * 128;
  float a0 = 0.f, a1 = 0.f, ab = 0.f;
  for (int k = k0; k < k0 + 128; ++k) {
    float w = lstm_W[(size_t)k * N4 + c];
    a0 += M_W[k] * w;
    a1 += M_W[NG + k] * w;
    ab += M_b[k] * w;
  }
  float* p = part + (size_t)kc * 3 * N4;
  p[c] = a0; p[N4 + c] = a1; p[2 * N4 + c] = ab;
}

__global__ __launch_bounds__(256) void k_prep_xw_reduce(
    const float* __restrict__ part, const float* __restrict__ lstm_b,
    float* __restrict__ W2r, float* __restrict__ b2r) {
  int c = blockIdx.x * 256 + threadIdx.x;
  float a0 = 0.f, a1 = 0.f, ab = 0.f;
  for (int kc = 0; kc < 16; ++kc) {
    const float* p = part + (size_t)kc * 3 * N4;
    a0 += p[c]; a1 += p[N4 + c]; ab += p[2 * N4 + c];
  }
  int n = ((c & 2047) << 2) | (c >> 11);
  W2r[n] = a0; W2r[N4 + n] = a1; b2r[n] = ab + lstm_b[c];
}

// ---- encoders: [h0 | c0] = p0 @ [enc1_W ; enc2_W] packed as N=4096 ----
__global__ __launch_bounds__(512) void k_enc(
    const unsigned short* __restrict__ p0b, const unsigned short* __restrict__ encWt,
    const float* __restrict__ enc1_b, const float* __restrict__ enc2_b,
    unsigned short* __restrict__ hbf, float* __restrict__ cfp) {
  __shared__ __align__(16) unsigned short sA[2 * 64 * 64];
  __shared__ __align__(16) unsigned short sB[2 * 128 * 64];
  int m0 = blockIdx.x * 64, n0 = blockIdx.y * 128;
  const f32x4 vzero = {0.f, 0.f, 0.f, 0.f};
  f32x4 acc[4];
#pragma unroll
  for (int i = 0; i < 4; ++i) acc[i] = vzero;
  gemm_core_p<64>(p0b, NP, m0, encWt, NP, n0, NP, sA, sB, acc);

  const int tid = threadIdx.x, wave = tid >> 6, lane = tid & 63;
  const int quad = lane >> 4, lr = lane & 15, wm = wave >> 2, wn = wave & 3;
#pragma unroll
  for (int fm = 0; fm < 2; ++fm)
#pragma unroll
    for (int fn = 0; fn < 2; ++fn)
#pragma unroll
      for (int reg = 0; reg < 4; ++reg) {
        int grow = m0 + wm * 32 + fm * 16 + quad * 4 + reg;
        int gcol = n0 + wn * 32 + fn * 16 + lr;
        float val = acc[fm * 2 + fn][reg];
        if (gcol < NG)
          hbf[(size_t)grow * NG + gcol] = f32_to_bf16(val + enc1_b[gcol]);
        else
          cfp[(size_t)grow * NG + (gcol - NG)] = val + enc2_b[gcol - NG];
      }
}

// ---- persistent recurrence: all 100 LSTM steps ----
// 256 blocks (4 mt x 64 nt, XCD swizzle), 512 threads, tile 64x128.
// Ring-4 LDS (A 4x8KB, B 4x16KB = 96KB), lookahead 3, raw s_barrier +
// counted vmcnt (loads stay in flight across barriers). No fences: Ut
// stays L2-resident for all 100 steps. h flows through hs: written once
// per step with sc1 write-through 4B atomic stores, read next step with
// plain cached loads (first touch -> no stale L2 copy possible).
__global__ __launch_bounds__(512) void k_steps(
    const unsigned short* __restrict__ Ut,
    const float* __restrict__ vv, const float* __restrict__ W2r,
    const float* __restrict__ b2r, float* __restrict__ cfp,
    const unsigned short* __restrict__ hb0,
    unsigned short* __restrict__ hs, unsigned* __restrict__ bar) {
  // smem: sA ring4 @0 (32KB), sB ring4 @32768 (64KB). After the K-loop the
  // front is reused as zs[64][132] f32 (33.8KB) + htmp @33792 (4KB).
  __shared__ __align__(16) char smem[98304];

  const int bid = blockIdx.x;           // XCD swizzle keeps Ut panel L2-resident
  const int xcd = bid & 7, sb = bid >> 3;
  const int mt = sb >> 3, nsub = sb & 7;
  const int nt = xcd * 8 + nsub;
  const int m0 = mt * 64, n0 = nt * 128;
  const int tid = threadIdx.x;
  const int wave = tid >> 6, lane = tid & 63;
  const int quad = lane >> 4, lr = lane & 15, wm = wave >> 2, wn = wave & 3;
  const int lr8 = lane >> 3, lc8 = lane & 7;
  const int scol = (lc8 ^ lr8) << 3;

  // gate-epilogue constants, invariant over t
  const int j = tid & 31;
  const int gbase = n0 + 4 * j;
  const float4 w2a   = *(const float4*)(W2r + gbase);
  const float4 w2b   = *(const float4*)(W2r + N4 + gbase);
  const float4 bbias = *(const float4*)(b2r + gbase);
  const int cell = (n0 >> 2) + j;
  const int r0 = tid >> 5;

  // drain prologue loads so in-loop vmcnt counting is exact
  asm volatile("s_waitcnt vmcnt(0)" ::: "memory");

  for (int t = 0; t < TT; ++t) {
    const unsigned short* hin = (t == 0) ? hb0 : (hs + (size_t)(t - 1) * BB * NG);

    const f32x4 vzero = {0.f, 0.f, 0.f, 0.f};
    f32x4 acc[4];
#pragma unroll
    for (int i = 0; i < 4; ++i) acc[i] = vzero;

    auto stageS = [&](int kt) {   // 3 vmem ops per wave per call
      const int slot = kt & 3;
      const int k0 = kt << 6;
      {
        const int rbase = wave * 8;
        const unsigned short* g = hin + (size_t)(m0 + rbase + lr8) * NG + (k0 + scol);
        async16(g, smem + slot * 8192 + rbase * 128);
      }
#pragma unroll
      for (int c = 0; c < 2; ++c) {
        const int rbase = wave * 16 + c * 8;
        const unsigned short* g = Ut + (size_t)(n0 + rbase + lr8) * NG + (k0 + scol);
        async16(g, smem + 32768 + slot * 16384 + rbase * 128);
      }
    };
    auto computeS = [&](int kt) {
      const char* cA = smem + (kt & 3) * 8192;
      const char* cB = smem + 32768 + (kt & 3) * 16384;
#pragma unroll
      for (int ks = 0; ks < 2; ++ks) {
        s16x8 af[2], bfr[2];
#pragma unroll
        for (int fm = 0; fm < 2; ++fm) {
          const int row = wm * 32 + fm * 16 + lr;
          af[fm] = *(const s16x8*)(cA + row * 128 + ((ks * 64 + quad * 16) ^ ((row & 7) << 4)));
        }
#pragma unroll
        for (int fn = 0; fn < 2; ++fn) {
          const int col = wn * 32 + fn * 16 + lr;
          bfr[fn] = *(const s16x8*)(cB + col * 128 + ((ks * 64 + quad * 16) ^ ((col & 7) << 4)));
        }
#pragma unroll
        for (int fm = 0; fm < 2; ++fm)
#pragma unroll
          for (int fn = 0; fn < 2; ++fn)
            acc[fm * 2 + fn] = mfma16(af[fm], bfr[fn], acc[fm * 2 + fn]);
      }
    };

    stageS(0); stageS(1); stageS(2);
    for (int kt = 0; kt < 29; ++kt) {
      // B1: all waves consumed iter kt-1's LDS -> safe to overwrite slot
      asm volatile("s_barrier" ::: "memory");
      stageS(kt + 3);
      // B2: own stage(kt) drained (<=9 newer ops) + all waves at same point
      asm volatile("s_waitcnt vmcnt(9)\n\ts_barrier" ::: "memory");
      computeS(kt);
    }
    asm volatile("s_waitcnt vmcnt(6)\n\ts_barrier" ::: "memory");
    computeS(29);
    asm volatile("s_waitcnt vmcnt(3)\n\ts_barrier" ::: "memory");
    computeS(30);
    asm volatile("s_waitcnt vmcnt(0)\n\ts_barrier" ::: "memory");
    computeS(31);
    __syncthreads();                 // all waves done with LDS before zs overwrite

    // phase 1: z -> LDS
    float* zs = (float*)smem;
#pragma unroll
    for (int fm = 0; fm < 2; ++fm)
#pragma unroll
      for (int fn = 0; fn < 2; ++fn)
#pragma unroll
        for (int reg = 0; reg < 4; ++reg) {
          const int r  = wm * 32 + fm * 16 + quad * 4 + reg;
          const int cc = wn * 32 + fn * 16 + lr;
          zs[r * 132 + cc] = acc[fm * 2 + fn][reg];
        }
    __syncthreads();
    // phase 2: gate update, h -> htmp (LDS)
    unsigned short* htmp = (unsigned short*)(smem + 33792);
#pragma unroll
    for (int i = 0; i < 4; ++i) {
      const int r = r0 + i * 16;
      const int b = m0 + r;
      const float2 vb = *(const float2*)(vv + ((size_t)b * TT + t) * 2);
      float4 z4 = *(const float4*)(zs + r * 132 + 4 * j);
      float zi = z4.x + vb.x * w2a.x + vb.y * w2b.x + bbias.x;
      float zf = z4.y + vb.x * w2a.y + vb.y * w2b.y + bbias.y;
      float zg = z4.z + vb.x * w2a.z + vb.y * w2b.z + bbias.z;
      float zo = z4.w + vb.x * w2a.w + vb.y * w2b.w + bbias.w;
      float i_ = 1.f / (1.f + __expf(-zi));
      float f_ = 1.f / (1.f + __expf(-zf));
      float g_ = fmaxf(zg, 0.f);
      float o_ = 1.f / (1.f + __expf(-zo));
      const size_t ci = (size_t)b * NG + cell;
      float cn = f_ * cfp[ci] + i_ * g_;
      cfp[ci] = cn;
      htmp[r * 32 + j] = f32_to_bf16(o_ * fmaxf(cn, 0.f));
    }
    __syncthreads();
    // phase 3: coalesced 4B sc1 write-through h stores into hs[t]
    const unsigned* hw = (const unsigned*)htmp;
#pragma unroll
    for (int p = 0; p < 2; ++p) {
      const int q = tid + p * 512;       // 0..1023 uints (64 rows x 16)
      const int r = q >> 4, cq = q & 15;
      unsigned* hp = (unsigned*)(hs + ((size_t)t * BB + m0 + r) * NG + (n0 >> 2)) + cq;
      __hip_atomic_store(hp, hw[q], __ATOMIC_RELAXED, __HIP_MEMORY_SCOPE_AGENT);
    }
    if (t + 1 < TT) grid_barrier2(bar, xcd, t);
  }
}

// ---- g_cells = relu(hs @ dense_W + dense_b) -> bf16 ----
__global__ __launch_bounds__(512) void k_dense(
    const unsigned short* __restrict__ hs, const unsigned short* __restrict__ dWt,
    const float* __restrict__ dense_b, unsigned short* __restrict__ gc) {
  __shared__ __align__(16) unsigned short sA[2 * 128 * 64];
  __shared__ __align__(16) unsigned short sB[2 * 128 * 64];
  int bid = blockIdx.x;
  int mt = bid >> 4;
  int r4 = bid & 15;
  int nt = ((r4 & 7) << 1) | (r4 >> 3);   // fixed nt pair per XCD
  int m0 = mt * 128, n0 = nt * 128;
  const f32x4 vzero = {0.f, 0.f, 0.f, 0.f};
  f32x4 acc[8];
#pragma unroll
  for (int i = 0; i < 8; ++i) acc[i] = vzero;
  gemm_core_p<128>(hs, NG, m0, dWt, NG, n0, NG, sA, sB, acc);

  const int tid = threadIdx.x, wave = tid >> 6, lane = tid & 63;
  const int quad = lane >> 4, lr = lane & 15, wm = wave >> 2, wn = wave & 3;
#pragma unroll
  for (int fm = 0; fm < 4; ++fm)
#pragma unroll
    for (int fn = 0; fn < 2; ++fn)
#pragma unroll
      for (int reg = 0; reg < 4; ++reg) {
        int grow = m0 + wm * 64 + fm * 16 + quad * 4 + reg;
        int gcol = n0 + wn * 32 + fn * 16 + lr;
        float val = fmaxf(acc[fm * 2 + fn][reg] + dense_b[gcol], 0.f);
        gc[(size_t)grow * NG + gcol] = f32_to_bf16(val);
      }
}

// ---- place_preds = g_cells @ dec_W + dec_b (fp32 out, [B][T][Np]) ----
__global__ __launch_bounds__(512) void k_dec(
    const unsigned short* __restrict__ gc, const unsigned short* __restrict__ decWt,
    const float* __restrict__ dec_b, float* __restrict__ out) {
  __shared__ __align__(16) unsigned short sA[2 * 128 * 64];
  __shared__ __align__(16) unsigned short sB[2 * 128 * 64];
  int m0 = blockIdx.x * 128, n0 = blockIdx.y * 128;
  const f32x4 vzero = {0.f, 0.f, 0.f, 0.f};
  f32x4 acc[8];
#pragma unroll
  for (int i = 0; i < 8; ++i) acc[i] = vzero;
  gemm_core_p<128>(gc, NG, m0, decWt, NG, n0, NG, sA, sB, acc);

  const int tid = threadIdx.x, wave = tid >> 6, lane = tid & 63;
  const int quad = lane >> 4, lr = lane & 15, wm = wave >> 2, wn = wave & 3;
#pragma unroll
  for (int fm = 0; fm < 4; ++fm)
#pragma unroll
    for (int fn = 0; fn < 2; ++fn)
#pragma unroll
      for (int reg = 0; reg < 4; ++reg) {
        int grow = m0 + wm * 64 + fm * 16 + quad * 4 + reg;   // t*256+b
        int gcol = n0 + wn * 32 + fn * 16 + lr;               // 0..511
        int tt = grow >> 8, b = grow & 255;
        out[((size_t)b * TT + tt) * NP + gcol] = acc[fm * 2 + fn][reg] + dec_b[gcol];
      }
}

// =====================================================================
extern "C" void kernel_launch(void* const* d_in, const int* in_sizes, int n_in,
                              void* d_out, int out_size, void* d_ws, size_t ws_size,
                              hipStream_t stream) {
  (void)in_sizes; (void)n_in; (void)out_size; (void)ws_size;
  const float* v       = (const float*)d_in[0];
  const float* p0      = (const float*)d_in[1];
  const float* enc1_W  = (const float*)d_in[2];
  const float* enc1_b  = (const float*)d_in[3];
  const float* enc2_W  = (const float*)d_in[4];
  const float* enc2_b  = (const float*)d_in[5];
  const float* M_W     = (const float*)d_in[6];
  const float* M_b     = (const float*)d_in[7];
  const float* lstm_W  = (const float*)d_in[8];
  const float* lstm_U  = (const float*)d_in[9];
  const float* lstm_b  = (const float*)d_in[10];
  const float* dense_W = (const float*)d_in[11];
  const float* dense_b = (const float*)d_in[12];
  const float* dec_W   = (const float*)d_in[13];
  const float* dec_b   = (const float*)d_in[14];
  float* out = (float*)d_out;

  char* ws = (char*)d_ws;
  size_t off = 0;
  auto alloc = [&](size_t bytes) {
    char* p = ws + off;
    off += (bytes + 255) & ~(size_t)255;
    return p;
  };
  unsigned short* Ut    = (unsigned short*)alloc((size_t)N4 * NG * 2);   // 32 MB
  unsigned short* dWt   = (unsigned short*)alloc((size_t)NG * NG * 2);   // 8 MB
  unsigned short* decWt = (unsigned short*)alloc((size_t)NP * NG * 2);   // 2 MB
  unsigned short* encWt = (unsigned short*)alloc((size_t)2 * NG * NP * 2);
  unsigned short* p0b   = (unsigned short*)alloc((size_t)BB * NP * 2);
  float* W2r  = (float*)alloc((size_t)2 * N4 * 4);
  float* b2r  = (float*)alloc((size_t)N4 * 4);
  float* part = (float*)alloc((size_t)16 * 3 * N4 * 4);
  float* cfp  = (float*)alloc((size_t)BB * NG * 4);
  unsigned short* hb0 = (unsigned short*)alloc((size_t)BB * NG * 2);
  unsigned short* hs  = (unsigned short*)alloc((size_t)MR * NG * 2);     // 100 MB
  unsigned short* gc  = (unsigned short*)alloc((size_t)MR * NG * 2);     // 100 MB
  unsigned* bar = (unsigned*)alloc(1024);                                // barrier words

  dim3 blk(256), blk5(512);
  // barrier init (fresh every launch/replay)
  k_zero<<<dim3(1), blk, 0, stream>>>(bar);
  // weight conversion / transposes
  k_transpose_bf16<1><<<dim3(32, 128), blk, 0, stream>>>(lstm_U, Ut, NG, N4, 0);
  k_transpose_bf16<0><<<dim3(32, 32), blk, 0, stream>>>(dense_W, dWt, NG, NG, 0);
  k_transpose_bf16<0><<<dim3(32, 8), blk, 0, stream>>>(dec_W, decWt, NG, NP, 0);
  k_transpose_bf16<0><<<dim3(8, 32), blk, 0, stream>>>(enc1_W, encWt, NP, NG, 0);
  k_transpose_bf16<0><<<dim3(8, 32), blk, 0, stream>>>(enc2_W, encWt, NP, NG, NG);
  k_cvt<<<dim3(512), blk, 0, stream>>>(p0, p0b, BB * NP);
  // rank-2 collapse of input path
  k_prep_xw_part<<<dim3(32, 16), blk, 0, stream>>>(lstm_W, M_W, M_b, part);
  k_prep_xw_reduce<<<dim3(32), blk, 0, stream>>>(part, lstm_b, W2r, b2r);
  // initial state
  k_enc<<<dim3(4, 32), blk5, 0, stream>>>(p0b, encWt, enc1_b, enc2_b, hb0, cfp);
  // recurrence: one persistent kernel, 100 steps, software grid barrier
  k_steps<<<dim3(NBLK), blk5, 0, stream>>>(Ut, v, W2r, b2r, cfp, hb0, hs, bar);
  // readout
  k_dense<<<dim3(3200), blk5, 0, stream>>>(hs, dWt, dense_b, gc);
  k_dec<<<dim3(200, 4), blk5, 0, stream>>>(gc, decWt, dec_b, out);
}

// Round 5
// 2090.987 us; speedup vs baseline: 5.8141x; 1.0209x over previous
//
#include <hip/hip_runtime.h>
#include <stdint.h>

#define DI __device__ __forceinline__

typedef short s16x8 __attribute__((ext_vector_type(8)));
typedef float f32x4 __attribute__((ext_vector_type(4)));

// ---- constants ----
#define NG   2048
#define NP   512
#define TT   100
#define BB   256
#define N4   8192   // 4*NG
#define MR   25600  // B*T
#define NBLK 256    // persistent grid size

DI unsigned short f32_to_bf16(float f) {
  union { float f; uint32_t u; } x; x.f = f;
  uint32_t r = x.u + 0x7fffu + ((x.u >> 16) & 1u);
  return (unsigned short)(r >> 16);
}

DI void async16(const void* g, void* l) {
  __builtin_amdgcn_global_load_lds((const __attribute__((address_space(1))) void*)g,
                                   (__attribute__((address_space(3))) void*)l,
                                   16, 0, 0);
}
DI void async4(const void* g, void* l) {
  __builtin_amdgcn_global_load_lds((const __attribute__((address_space(1))) void*)g,
                                   (__attribute__((address_space(3))) void*)l,
                                   4, 0, 0);
}

DI f32x4 mfma16(s16x8 a, s16x8 b, f32x4 c) {
  return __builtin_amdgcn_mfma_f32_16x16x32_bf16(a, b, c, 0, 0, 0);
}

__global__ __launch_bounds__(256) void k_zero(unsigned* p) {
  if (threadIdx.x < 160) p[threadIdx.x] = 0u;
}

// ---- software grid barrier: monotonic counters, RELAXED agent atomics ----
// No fences: cross-XCD data (hs) moves via write-through stores (drained by
// vmcnt(0) before arrival) and first-touch cached reads.
DI void grid_barrier2(unsigned* bar, int xcd, int t) {
  asm volatile("s_waitcnt vmcnt(0)" ::: "memory");  // h-stores globally visible
  __syncthreads();
  if (threadIdx.x == 0) {
    unsigned a = __hip_atomic_fetch_add(bar + xcd * 16, 1u,
                                        __ATOMIC_RELAXED, __HIP_MEMORY_SCOPE_AGENT);
    if (a + 1u == 32u * (unsigned)(t + 1)) {        // last block of this XCD
      unsigned g2 = __hip_atomic_fetch_add(bar + 128, 1u,
                                           __ATOMIC_RELAXED, __HIP_MEMORY_SCOPE_AGENT);
      if (g2 + 1u == 8u * (unsigned)(t + 1))        // last XCD
        __hip_atomic_store(bar + 144, (unsigned)(t + 1),
                           __ATOMIC_RELAXED, __HIP_MEMORY_SCOPE_AGENT);
    }
    while (__hip_atomic_load(bar + 144, __ATOMIC_RELAXED,
                             __HIP_MEMORY_SCOPE_AGENT) < (unsigned)(t + 1))
      __builtin_amdgcn_s_sleep(8);
  }
  __syncthreads();
}

// =====================================================================
// Pipelined bf16 MFMA core (non-persistent kernels) — unchanged.
// =====================================================================
template <int BM>
DI void gemm_core_p(const unsigned short* __restrict__ A, int lda, int m0,
                    const unsigned short* __restrict__ Bt, int ldb, int n0, int K,
                    unsigned short* sA, unsigned short* sB, f32x4* acc) {
  constexpr int FM = BM / 32;
  const int tid  = threadIdx.x;
  const int wave = tid >> 6;
  const int lane = tid & 63;
  const int quad = lane >> 4;
  const int lr   = lane & 15;
  const int wm   = wave >> 2;
  const int wn   = wave & 3;
  const int lr8  = lane >> 3;
  const int lc8  = lane & 7;
  const int scol = (lc8 ^ lr8) << 3;

  const int nkt = K >> 6;
  int buf = 0;

  auto stage = [&](int bsel, int k0) {
    unsigned short* dA = sA + bsel * (BM * 64);
    unsigned short* dB = sB + bsel * (128 * 64);
#pragma unroll
    for (int c = 0; c < BM / 64; ++c) {
      int rbase = wave * (BM / 8) + c * 8;
      const unsigned short* g = A + (size_t)(m0 + rbase + lr8) * lda + (k0 + scol);
      async16(g, dA + rbase * 64);
    }
#pragma unroll
    for (int c = 0; c < 2; ++c) {
      int rbase = wave * 16 + c * 8;
      const unsigned short* g = Bt + (size_t)(n0 + rbase + lr8) * ldb + (k0 + scol);
      async16(g, dB + rbase * 64);
    }
  };

  stage(0, 0);
  __syncthreads();
  for (int kt = 0; kt < nkt; ++kt) {
    if (kt + 1 < nkt) stage(buf ^ 1, (kt + 1) << 6);
    const char* cA = (const char*)(sA + buf * (BM * 64));
    const char* cB = (const char*)(sB + buf * (128 * 64));
#pragma unroll
    for (int ks = 0; ks < 2; ++ks) {
      s16x8 af[FM], bfr[2];
#pragma unroll
      for (int fm = 0; fm < FM; ++fm) {
        int row = wm * (BM / 2) + fm * 16 + lr;
        int off = row * 128 + ((ks * 64 + quad * 16) ^ ((row & 7) << 4));
        af[fm] = *(const s16x8*)(cA + off);
      }
#pragma unroll
      for (int fn = 0; fn < 2; ++fn) {
        int col = wn * 32 + fn * 16 + lr;
        int off = col * 128 + ((ks * 64 + quad * 16) ^ ((col & 7) << 4));
        bfr[fn] = *(const s16x8*)(cB + off);
      }
#pragma unroll
      for (int fm = 0; fm < FM; ++fm)
#pragma unroll
        for (int fn = 0; fn < 2; ++fn)
          acc[fm * 2 + fn] = mfma16(af[fm], bfr[fn], acc[fm * 2 + fn]);
    }
    __syncthreads();
    buf ^= 1;
  }
}

// =====================================================================
// Transpose + fp32->bf16. MODE 0: n = c + noff. MODE 1 (lstm_U gate/cell
// permutation): n = ((c&2047)>>4)*64 + ((c>>11)<<4) + (c&15)  — each
// 64-col group = 16 cells x 4 gates, so one lane's acc holds all 4 gates.
// =====================================================================
template <int MODE>
__global__ __launch_bounds__(256) void k_transpose_bf16(
    const float* __restrict__ src, unsigned short* __restrict__ dst,
    int R, int C, int noff) {
  __shared__ unsigned short tile[64][65];
  int tr0 = blockIdx.x * 64;
  int tc0 = blockIdx.y * 64;
  int tid = threadIdx.x;
#pragma unroll
  for (int i = 0; i < 16; ++i) {
    int idx = tid + i * 256;
    int r = idx >> 6, c = idx & 63;
    tile[r][c] = f32_to_bf16(src[(size_t)(tr0 + r) * C + (tc0 + c)]);
  }
  __syncthreads();
#pragma unroll
  for (int i = 0; i < 16; ++i) {
    int idx = tid + i * 256;
    int cc = idx >> 6, r = idx & 63;
    int c = tc0 + cc;
    int n = (MODE == 0) ? (c + noff)
                        : ((((c & 2047) >> 4) << 6) | (((c >> 11) & 3) << 4) | (c & 15));
    dst[(size_t)n * R + (tr0 + r)] = tile[r][cc];
  }
}

__global__ __launch_bounds__(256) void k_cvt(const float* __restrict__ src,
                                             unsigned short* __restrict__ dst, int n) {
  int i = blockIdx.x * 256 + threadIdx.x;
  if (i < n) dst[i] = f32_to_bf16(src[i]);
}

// ---- W2 = M_W @ lstm_W, bias2 = M_b @ lstm_W + lstm_b (gate-permuted) ----
__global__ __launch_bounds__(256) void k_prep_xw_part(
    const float* __restrict__ lstm_W, const float* __restrict__ M_W,
    const float* __restrict__ M_b, float* __restrict__ part) {
  int c = blockIdx.x * 256 + threadIdx.x;
  int kc = blockIdx.y;
  int k0 = kc * 128;
  float a0 = 0.f, a1 = 0.f, ab = 0.f;
  for (int k = k0; k < k0 + 128; ++k) {
    float w = lstm_W[(size_t)k * N4 + c];
    a0 += M_W[k] * w;
    a1 += M_W[NG + k] * w;
    ab += M_b[k] * w;
  }
  float* p = part + (size_t)kc * 3 * N4;
  p[c] = a0; p[N4 + c] = a1; p[2 * N4 + c] = ab;
}

__global__ __launch_bounds__(256) void k_prep_xw_reduce(
    const float* __restrict__ part, const float* __restrict__ lstm_b,
    float* __restrict__ W2r, float* __restrict__ b2r) {
  int c = blockIdx.x * 256 + threadIdx.x;
  float a0 = 0.f, a1 = 0.f, ab = 0.f;
  for (int kc = 0; kc < 16; ++kc) {
    const float* p = part + (size_t)kc * 3 * N4;
    a0 += p[c]; a1 += p[N4 + c]; ab += p[2 * N4 + c];
  }
  int n = (((c & 2047) >> 4) << 6) | (((c >> 11) & 3) << 4) | (c & 15);
  W2r[n] = a0; W2r[N4 + n] = a1; b2r[n] = ab + lstm_b[c];
}

// ---- encoders: [h0 | c0] = p0 @ [enc1_W ; enc2_W] packed as N=4096 ----
__global__ __launch_bounds__(512) void k_enc(
    const unsigned short* __restrict__ p0b, const unsigned short* __restrict__ encWt,
    const float* __restrict__ enc1_b, const float* __restrict__ enc2_b,
    unsigned short* __restrict__ hbf, float* __restrict__ cfp) {
  __shared__ __align__(16) unsigned short sA[2 * 64 * 64];
  __shared__ __align__(16) unsigned short sB[2 * 128 * 64];
  int m0 = blockIdx.x * 64, n0 = blockIdx.y * 128;
  const f32x4 vzero = {0.f, 0.f, 0.f, 0.f};
  f32x4 acc[4];
#pragma unroll
  for (int i = 0; i < 4; ++i) acc[i] = vzero;
  gemm_core_p<64>(p0b, NP, m0, encWt, NP, n0, NP, sA, sB, acc);

  const int tid = threadIdx.x, wave = tid >> 6, lane = tid & 63;
  const int quad = lane >> 4, lr = lane & 15, wm = wave >> 2, wn = wave & 3;
#pragma unroll
  for (int fm = 0; fm < 2; ++fm)
#pragma unroll
    for (int fn = 0; fn < 2; ++fn)
#pragma unroll
      for (int reg = 0; reg < 4; ++reg) {
        int grow = m0 + wm * 32 + fm * 16 + quad * 4 + reg;
        int gcol = n0 + wn * 32 + fn * 16 + lr;
        float val = acc[fm * 2 + fn][reg];
        if (gcol < NG)
          hbf[(size_t)grow * NG + gcol] = f32_to_bf16(val + enc1_b[gcol]);
        else
          cfp[(size_t)grow * NG + (gcol - NG)] = val + enc2_b[gcol - NG];
      }
}

// ---- persistent recurrence: all 100 LSTM steps ----
// 256 blocks (4 mt x 64 nt, XCD swizzle), 256 threads (4 waves, 2x2 of
// 32x64 wave tiles). Ring-5 LDS, single barrier per phase, counted vmcnt,
// cross-step Ut prefetch, register gate epilogue (c state in VGPRs).
__global__ __launch_bounds__(256) void k_steps(
    const unsigned short* __restrict__ Ut,
    const float* __restrict__ vv, const float* __restrict__ W2r,
    const float* __restrict__ b2r, const float* __restrict__ cfp,
    const unsigned short* __restrict__ hb0,
    unsigned short* __restrict__ hs, unsigned* __restrict__ bar) {
  // A ring5 @0 (5x8KB), B ring5 @40960 (5x16KB), vvx @122880, vvy @123136,
  // htmp @123392 (4KB) -> 127488 B
  __shared__ __align__(16) char smem[127488];

  const int bid = blockIdx.x;
  const int xcd = bid & 7, sb = bid >> 3;
  const int mt = sb >> 3, nsub = sb & 7;
  const int nt = xcd * 8 + nsub;
  const int m0 = mt * 64, n0 = nt * 128;
  const int tid = threadIdx.x;
  const int wave = tid >> 6, lane = tid & 63;
  const int quad = lane >> 4, lr = lane & 15;
  const int wm = wave >> 1, wn = wave & 1;
  const int lr8 = lane >> 3, lc8 = lane & 7;
  const int scol = (lc8 ^ lr8) << 3;

  // ---- t-invariant state in registers ----
  float w2x[4], w2y[4], bz[4];
#pragma unroll
  for (int g = 0; g < 4; ++g) {
    const int idx = n0 + wn * 64 + g * 16 + lr;
    w2x[g] = W2r[idx]; w2y[g] = W2r[N4 + idx]; bz[g] = b2r[idx];
    asm volatile("" : "+v"(w2x[g])); asm volatile("" : "+v"(w2y[g]));
    asm volatile("" : "+v"(bz[g]));
  }
  const int cellg = nt * 32 + wn * 16 + lr;       // this thread's cell
  float cst[2][4];
#pragma unroll
  for (int fm = 0; fm < 2; ++fm)
#pragma unroll
    for (int reg = 0; reg < 4; ++reg) {
      const int r = wm * 32 + fm * 16 + quad * 4 + reg;
      cst[fm][reg] = cfp[(size_t)(m0 + r) * NG + cellg];
      asm volatile("" : "+v"(cst[fm][reg]));
    }

  auto stageA = [&](int slot, int kt, const unsigned short* hin) {  // 2 ops
#pragma unroll
    for (int c = 0; c < 2; ++c) {
      const int rb = wave * 16 + c * 8;
      const unsigned short* g = hin + (size_t)(m0 + rb + lr8) * NG + ((kt << 6) + scol);
      async16(g, smem + slot * 8192 + rb * 128);
    }
  };
  auto stageB = [&](int slot, int k) {            // 4 ops
#pragma unroll
    for (int c = 0; c < 4; ++c) {
      const int rb = wave * 32 + c * 8;
      const unsigned short* g = Ut + (size_t)(n0 + rb + lr8) * NG + (k + scol);
      async16(g, smem + 40960 + slot * 16384 + rb * 128);
    }
  };
  auto stageV = [&](int t) {                      // 2 ops (all waves duplicate)
    const float* gx = vv + ((size_t)(m0 + lane) * TT + t) * 2;
    async4(gx, smem + 122880);
    async4(gx + 1, smem + 123136);
  };

  f32x4 acc[8];
  auto computeS = [&](int slot) {
    const char* cA = smem + slot * 8192;
    const char* cB = smem + 40960 + slot * 16384;
#pragma unroll
    for (int ks = 0; ks < 2; ++ks) {
      s16x8 af[2], bfr[4];
#pragma unroll
      for (int fm = 0; fm < 2; ++fm) {
        const int row = wm * 32 + fm * 16 + lr;
        af[fm] = *(const s16x8*)(cA + row * 128 + ((ks * 64 + quad * 16) ^ ((row & 7) << 4)));
      }
#pragma unroll
      for (int fn = 0; fn < 4; ++fn) {
        const int col = wn * 64 + fn * 16 + lr;
        bfr[fn] = *(const s16x8*)(cB + col * 128 + ((ks * 64 + quad * 16) ^ ((col & 7) << 4)));
      }
#pragma unroll
      for (int fm = 0; fm < 2; ++fm)
#pragma unroll
        for (int fn = 0; fn < 4; ++fn)
          acc[fm * 4 + fn] = mfma16(af[fm], bfr[fn], acc[fm * 4 + fn]);
    }
  };

#define INC5(x) x = ((x) == 4) ? 0 : ((x) + 1)
#define PHASE(W)  asm volatile("s_waitcnt vmcnt(" #W ")\n\ts_barrier" ::: "memory"); \
                  computeS(cs); INC5(cs);

  asm volatile("s_waitcnt vmcnt(0)" ::: "memory");  // exact counting baseline
  int cs = 0;
  // t=0: B slots 0,1,2
  stageB(0, 0); stageB(1, 64); stageB(2, 128);

  for (int t = 0; t < TT; ++t) {
    const unsigned short* hin = t ? hs + (size_t)(t - 1) * BB * NG : hb0;
    // entry: A into slots cs..cs+2 (their B is already prefetched)
    {
      int s1 = cs; stageA(s1, 0, hin); INC5(s1);
      stageA(s1, 1, hin); INC5(s1);
      stageA(s1, 2, hin);
    }
    stageV(t);
    const f32x4 vzero = {0.f, 0.f, 0.f, 0.f};
#pragma unroll
    for (int i = 0; i < 8; ++i) acc[i] = vzero;

    int ss = cs; INC5(ss); INC5(ss); INC5(ss);    // stage slot = cs+3
    // phases 0..2 (entry counts include A-entry + vv)
    stageB(ss, 3 << 6); stageA(ss, 3, hin); INC5(ss);
    PHASE(12)
    stageB(ss, 4 << 6); stageA(ss, 4, hin); INC5(ss);
    PHASE(16)
    stageB(ss, 5 << 6); stageA(ss, 5, hin); INC5(ss);
    PHASE(20)
    // phases 3..28 (steady)
    for (int p = 3; p <= 28; ++p) {
      stageB(ss, (p + 3) << 6); stageA(ss, p + 3, hin); INC5(ss);
      PHASE(18)
    }
    // phases 29..31: B-only prefetch of NEXT step's k = 0,64,128
    stageB(ss, 0); INC5(ss);
    PHASE(16)
    stageB(ss, 64); INC5(ss);
    PHASE(14)
    stageB(ss, 128); INC5(ss);
    PHASE(12)

    // ---- register gate epilogue ----
    const float* vx = (const float*)(smem + 122880);
    const float* vy = (const float*)(smem + 123136);
    unsigned short* htmp = (unsigned short*)(smem + 123392);
#pragma unroll
    for (int fm = 0; fm < 2; ++fm)
#pragma unroll
      for (int reg = 0; reg < 4; ++reg) {
        const int r = wm * 32 + fm * 16 + quad * 4 + reg;
        const float ax = vx[r], ay = vy[r];
        float zi = acc[fm * 4 + 0][reg] + ax * w2x[0] + ay * w2y[0] + bz[0];
        float zf = acc[fm * 4 + 1][reg] + ax * w2x[1] + ay * w2y[1] + bz[1];
        float zg = acc[fm * 4 + 2][reg] + ax * w2x[2] + ay * w2y[2] + bz[2];
        float zo = acc[fm * 4 + 3][reg] + ax * w2x[3] + ay * w2y[3] + bz[3];
        float i_ = 1.f / (1.f + __expf(-zi));
        float f_ = 1.f / (1.f + __expf(-zf));
        float g_ = fmaxf(zg, 0.f);
        float o_ = 1.f / (1.f + __expf(-zo));
        float cn = f_ * cst[fm][reg] + i_ * g_;
        cst[fm][reg] = cn;
        htmp[r * 32 + wn * 16 + lr] = f32_to_bf16(o_ * fmaxf(cn, 0.f));
      }
    __syncthreads();
    // coalesced 4B write-through h stores into hs[t]
    const unsigned* hw = (const unsigned*)htmp;
#pragma unroll
    for (int p = 0; p < 4; ++p) {
      const int q = tid + p * 256;       // 0..1023 uints (64 rows x 16)
      const int r = q >> 4, cq = q & 15;
      unsigned* hp = (unsigned*)(hs + ((size_t)t * BB + m0 + r) * NG) + (nt * 16 + cq);
      __hip_atomic_store(hp, hw[q], __ATOMIC_RELAXED, __HIP_MEMORY_SCOPE_AGENT);
    }
    if (t + 1 < TT) grid_barrier2(bar, xcd, t);   // drains everything (vmcnt 0)
  }
#undef PHASE
#undef INC5
}

// ---- g_cells = relu(hs @ dense_W + dense_b) -> bf16 ----
__global__ __launch_bounds__(512) void k_dense(
    const unsigned short* __restrict__ hs, const unsigned short* __restrict__ dWt,
    const float* __restrict__ dense_b, unsigned short* __restrict__ gc) {
  __shared__ __align__(16) unsigned short sA[2 * 128 * 64];
  __shared__ __align__(16) unsigned short sB[2 * 128 * 64];
  int bid = blockIdx.x;
  int mt = bid >> 4;
  int r4 = bid & 15;
  int nt = ((r4 & 7) << 1) | (r4 >> 3);   // fixed nt pair per XCD
  int m0 = mt * 128, n0 = nt * 128;
  const f32x4 vzero = {0.f, 0.f, 0.f, 0.f};
  f32x4 acc[8];
#pragma unroll
  for (int i = 0; i < 8; ++i) acc[i] = vzero;
  gemm_core_p<128>(hs, NG, m0, dWt, NG, n0, NG, sA, sB, acc);

  const int tid = threadIdx.x, wave = tid >> 6, lane = tid & 63;
  const int quad = lane >> 4, lr = lane & 15, wm = wave >> 2, wn = wave & 3;
#pragma unroll
  for (int fm = 0; fm < 4; ++fm)
#pragma unroll
    for (int fn = 0; fn < 2; ++fn)
#pragma unroll
      for (int reg = 0; reg < 4; ++reg) {
        int grow = m0 + wm * 64 + fm * 16 + quad * 4 + reg;
        int gcol = n0 + wn * 32 + fn * 16 + lr;
        float val = fmaxf(acc[fm * 2 + fn][reg] + dense_b[gcol], 0.f);
        gc[(size_t)grow * NG + gcol] = f32_to_bf16(val);
      }
}

// ---- place_preds = g_cells @ dec_W + dec_b (fp32 out, [B][T][Np]) ----
__global__ __launch_bounds__(512) void k_dec(
    const unsigned short* __restrict__ gc, const unsigned short* __restrict__ decWt,
    const float* __restrict__ dec_b, float* __restrict__ out) {
  __shared__ __align__(16) unsigned short sA[2 * 128 * 64];
  __shared__ __align__(16) unsigned short sB[2 * 128 * 64];
  int m0 = blockIdx.x * 128, n0 = blockIdx.y * 128;
  const f32x4 vzero = {0.f, 0.f, 0.f, 0.f};
  f32x4 acc[8];
#pragma unroll
  for (int i = 0; i < 8; ++i) acc[i] = vzero;
  gemm_core_p<128>(gc, NG, m0, decWt, NG, n0, NG, sA, sB, acc);

  const int tid = threadIdx.x, wave = tid >> 6, lane = tid & 63;
  const int quad = lane >> 4, lr = lane & 15, wm = wave >> 2, wn = wave & 3;
#pragma unroll
  for (int fm = 0; fm < 4; ++fm)
#pragma unroll
    for (int fn = 0; fn < 2; ++fn)
#pragma unroll
      for (int reg = 0; reg < 4; ++reg) {
        int grow = m0 + wm * 64 + fm * 16 + quad * 4 + reg;   // t*256+b
        int gcol = n0 + wn * 32 + fn * 16 + lr;               // 0..511
        int tt = grow >> 8, b = grow & 255;
        out[((size_t)b * TT + tt) * NP + gcol] = acc[fm * 2 + fn][reg] + dec_b[gcol];
      }
}

// =====================================================================
extern "C" void kernel_launch(void* const* d_in, const int* in_sizes, int n_in,
                              void* d_out, int out_size, void* d_ws, size_t ws_size,
                              hipStream_t stream) {
  (void)in_sizes; (void)n_in; (void)out_size; (void)ws_size;
  const float* v       = (const float*)d_in[0];
  const float* p0      = (const float*)d_in[1];
  const float* enc1_W  = (const float*)d_in[2];
  const float* enc1_b  = (const float*)d_in[3];
  const float* enc2_W  = (const float*)d_in[4];
  const float* enc2_b  = (const float*)d_in[5];
  const float* M_W     = (const float*)d_in[6];
  const float* M_b     = (const float*)d_in[7];
  const float* lstm_W  = (const float*)d_in[8];
  const float* lstm_U  = (const float*)d_in[9];
  const float* lstm_b  = (const float*)d_in[10];
  const float* dense_W = (const float*)d_in[11];
  const float* dense_b = (const float*)d_in[12];
  const float* dec_W   = (const float*)d_in[13];
  const float* dec_b   = (const float*)d_in[14];
  float* out = (float*)d_out;

  char* ws = (char*)d_ws;
  size_t off = 0;
  auto alloc = [&](size_t bytes) {
    char* p = ws + off;
    off += (bytes + 255) & ~(size_t)255;
    return p;
  };
  unsigned short* Ut    = (unsigned short*)alloc((size_t)N4 * NG * 2);   // 32 MB
  unsigned short* dWt   = (unsigned short*)alloc((size_t)NG * NG * 2);   // 8 MB
  unsigned short* decWt = (unsigned short*)alloc((size_t)NP * NG * 2);   // 2 MB
  unsigned short* encWt = (unsigned short*)alloc((size_t)2 * NG * NP * 2);
  unsigned short* p0b   = (unsigned short*)alloc((size_t)BB * NP * 2);
  float* W2r  = (float*)alloc((size_t)2 * N4 * 4);
  float* b2r  = (float*)alloc((size_t)N4 * 4);
  float* part = (float*)alloc((size_t)16 * 3 * N4 * 4);
  float* cfp  = (float*)alloc((size_t)BB * NG * 4);
  unsigned short* hb0 = (unsigned short*)alloc((size_t)BB * NG * 2);
  unsigned short* hs  = (unsigned short*)alloc((size_t)MR * NG * 2);     // 100 MB
  unsigned short* gc  = (unsigned short*)alloc((size_t)MR * NG * 2);     // 100 MB
  unsigned* bar = (unsigned*)alloc(1024);                                // barrier words

  dim3 blk(256), blk5(512);
  // barrier init (fresh every launch/replay)
  k_zero<<<dim3(1), blk, 0, stream>>>(bar);
  // weight conversion / transposes
  k_transpose_bf16<1><<<dim3(32, 128), blk, 0, stream>>>(lstm_U, Ut, NG, N4, 0);
  k_transpose_bf16<0><<<dim3(32, 32), blk, 0, stream>>>(dense_W, dWt, NG, NG, 0);
  k_transpose_bf16<0><<<dim3(32, 8), blk, 0, stream>>>(dec_W, decWt, NG, NP, 0);
  k_transpose_bf16<0><<<dim3(8, 32), blk, 0, stream>>>(enc1_W, encWt, NP, NG, 0);
  k_transpose_bf16<0><<<dim3(8, 32), blk, 0, stream>>>(enc2_W, encWt, NP, NG, NG);
  k_cvt<<<dim3(512), blk, 0, stream>>>(p0, p0b, BB * NP);
  // rank-2 collapse of input path
  k_prep_xw_part<<<dim3(32, 16), blk, 0, stream>>>(lstm_W, M_W, M_b, part);
  k_prep_xw_reduce<<<dim3(32), blk, 0, stream>>>(part, lstm_b, W2r, b2r);
  // initial state
  k_enc<<<dim3(4, 32), blk5, 0, stream>>>(p0b, encWt, enc1_b, enc2_b, hb0, cfp);
  // recurrence: one persistent kernel, 100 steps
  k_steps<<<dim3(NBLK), blk, 0, stream>>>(Ut, v, W2r, b2r, cfp, hb0, hs, bar);
  // readout
  k_dense<<<dim3(3200), blk5, 0, stream>>>(hs, dWt, dense_b, gc);
  k_dec<<<dim3(200, 4), blk5, 0, stream>>>(gc, decWt, dec_b, out);
}